// Round 11
// baseline (112.442 us; speedup 1.0000x reference)
//
#include <hip/hip_runtime.h>

// MinEuclideanDistBlock: x(32,8,4096) f32, shapelets(8,128,64) f32 -> out(32,1,128) f32
// out[b,k] = min_w sum_c sqrt( xnorm[b,c,w] + snorm[c,k] - 2*sum_s x[b,c,w+s]*h[c,k,s] )
//
// R12 -> R13 (post-mortem: register model solved. Per-SIMD file = 256 wave64-regs;
// budget = 256/(waves/EU for one WG to fit): (256,2)->128, (256,3)->85, 1024t->64.
// Runtime residency = floor(256/VGPR) waves/SIMD: all session occupancies match.
// The wall: VGPR ~100 -> 2 waves/SIMD. Path: demand <= 85 -> 3 waves/SIMD, +50% TLP):
//  - K split ACROSS WAVES in the block (not across grid - R7's duplication mistake):
//    BDIM 256, WT 64; wave = (wrow = wv&1) window-half x (kh = wv>>1) K-half.
//    dist[2][4][4] = 32 regs; af/xn loaded per-mt (8+4 live). Demand ~78.
//  - Staging shared per block: full-K Bs[2][16KB] double-buffer, Xr[2][2.1KB],
//    xnorm 2KB, snorm 4KB = 42.25KB LDS (3 WGs fit by LDS too).
//  - Pipeline = R5's proven single-barrier-per-c-iter prefetch loop; inner
//    arithmetic byte-identical (same accumulation order -> same numerics).
//  - __launch_bounds__(256,3) pins budget 85 (R4-verified as 84).
//  - Tripwires: VGPR > 85 or WRITE_SIZE >> 2MB (spill) -> revert to R5 geometry.

typedef short short8 __attribute__((ext_vector_type(8)));
typedef float f32x4 __attribute__((ext_vector_type(4)));

constexpr int Bn = 32, Cn = 8, Ln = 4096, Kn = 128, Sn = 64;
constexpr int Wn = Ln - Sn + 1;          // 4033
constexpr int WT = 64;                   // windows per block
constexpr int NWT = (Wn + WT - 1) / WT;  // 64
constexpr int BDIM = 256;
constexpr int XRS = 136;                 // Xr row stride (elems); 272B = 17*16B, 68w = 4 mod 32
constexpr int PPR = 64;                  // pairs per Xr row (128 elems staged)
constexpr int PAIRS = 8 * PPR;           // 512 staged pairs per channel

typedef const __attribute__((address_space(1))) unsigned int gas_u32;
typedef __attribute__((address_space(3))) unsigned int las_u32;

__device__ __forceinline__ unsigned int f2bf(float f) {
  unsigned int u = __float_as_uint(f);
  u += 0x7FFFu + ((u >> 16) & 1u);       // round-to-nearest-even
  return u >> 16;
}

// ws layout: [0, 128KB): ushort hbf[C][K][S] = bf16(-2*h), byte-swizzled ^((k&7)<<4)
//            [128KB, +4KB): float snorm[C][K]
__global__ void prep_kernel(const float* __restrict__ sh,
                            unsigned int* __restrict__ out,
                            unsigned short* __restrict__ hbf,
                            float* __restrict__ snorm) {
  int gid = blockIdx.x * blockDim.x + threadIdx.x;  // 0..4095
  out[gid] = 0x7F7FFFFFu;                           // FLT_MAX bits (Bn*Kn == 4096)
  if (gid < Cn * Kn) {
    const float4* row = (const float4*)(sh + (size_t)gid * Sn);
    char* rowb = (char*)hbf + (size_t)gid * (Sn * 2);   // 128B row
    const unsigned int sw = (gid & 7u) << 4;            // (k&7)<<4 byte swizzle
    float a = 0.f;
    #pragma unroll
    for (int i = 0; i < 16; ++i) {
      float4 v = row[i];
      a += v.x * v.x + v.y * v.y + v.z * v.z + v.w * v.w;
      unsigned int p0 = f2bf(-2.f * v.x) | (f2bf(-2.f * v.y) << 16);
      unsigned int p1 = f2bf(-2.f * v.z) | (f2bf(-2.f * v.w) << 16);
      *(uint2*)(rowb + ((8u * i) ^ sw)) = make_uint2(p0, p1);  // stays 8B-aligned
    }
    snorm[gid] = a;
  }
}

__launch_bounds__(BDIM, 3)
__global__ void med_kernel(const float* __restrict__ x,
                           const unsigned short* __restrict__ hbf,
                           const float* __restrict__ snorm,
                           unsigned int* __restrict__ out) {
  __shared__ __align__(16) unsigned short Xr[2][8 * XRS];   // 2 x 2.125KB
  __shared__ __align__(16) unsigned short Bs[2][Kn * Sn];   // 2 x 16KB, swizzled
  __shared__ __align__(16) float xnormC[Cn * WT];           // 2KB
  __shared__ __align__(16) float snormC[Cn * Kn];           // 4KB

  const int tid  = threadIdx.x;
  const int b    = blockIdx.y;
  const int w0   = blockIdx.x * WT;
  const int lane = tid & 63;
  const int wv   = tid >> 6;     // wave 0..3
  const int quad = lane >> 4;    // 0..3
  const int n16  = lane & 15;
  const int wrow = wv & 1;       // window-half (32 windows)
  const int kh   = wv >> 1;      // K-half (64 shapelets)
  const int wbase = wrow * 32;

  const float* xb = x + (size_t)b * Cn * Ln;

  // ---- B staging: linear global->LDS DMA of pre-swizzled 16KB c-slice ----
  auto stage_b = [&](int bufi, int c) {
    const char* src = (const char*)hbf + (size_t)c * (Kn * Sn * 2);
    char* dst = (char*)&Bs[bufi][0];
    #pragma unroll
    for (int rep = 0; rep < 4; ++rep) {
      int q16 = (tid + rep * BDIM) * 16;   // lane-linear 16B chunks
      __builtin_amdgcn_global_load_lds((gas_u32*)(src + q16), (las_u32*)(dst + q16),
                                       16, 0, 0);
    }
  };

  // ---- X staging: c-invariant index math hoisted; load early / write late ----
  int x_lds[2], x_g[2];
  #pragma unroll
  for (int rep = 0; rep < 2; ++rep) {
    int pid = tid + rep * BDIM;       // 0..511
    int r = pid >> 6;                 // row 0..7
    int p = pid & 63;                 // pair index 0..63 -> elems 2p,2p+1
    x_lds[rep] = r * XRS + 2 * p;
    x_g[rep] = w0 + r + 2 * p;
  }
  float xf[2][2];
  auto load_x = [&](int c) {
    const float* xc = xb + (size_t)c * Ln;
    #pragma unroll
    for (int rep = 0; rep < 2; ++rep) {
      int i0 = x_g[rep];
      xf[rep][0] = (i0 < Ln) ? xc[i0] : 0.f;
      xf[rep][1] = (i0 + 1 < Ln) ? xc[i0 + 1] : 0.f;
    }
  };
  auto write_x = [&](int bufi) {
    #pragma unroll
    for (int rep = 0; rep < 2; ++rep)
      *(unsigned int*)(&Xr[bufi][x_lds[rep]]) =
          f2bf(xf[rep][0]) | (f2bf(xf[rep][1]) << 16);
  };

  // snorm: one float4 per thread from prep output
  ((float4*)snormC)[tid] = ((const float4*)snorm)[tid];

  // ---- prologue: stage c=0 into buf 0 (DMA overlaps xnorm compute) ----
  stage_b(0, 0);
  load_x(0);

  // xnorm: 256 threads = 8c x 32 groups, 2 windows each (rolling update), fp32-exact
  {
    int c  = tid >> 5;
    int m0 = (tid & 31) * 2;
    const float* xc = xb + c * Ln;
    auto xq = [&](int i) -> float {
      float v = (i < Ln) ? xc[i] : 0.f;
      return v * v;
    };
    float s0 = 0.f;
    for (int s = 0; s < Sn; ++s) s0 += xq(w0 + m0 + s);
    float s1 = s0 - xq(w0 + m0 + 0) + xq(w0 + m0 + 64);
    xnormC[c * WT + m0 + 0] = s0;
    xnormC[c * WT + m0 + 1] = s1;
  }
  write_x(0);
  __syncthreads();  // drains prologue DMA (implicit vmcnt(0)) + covers norm writes

  float dist[2][4][4] = {};  // [mtile][nt][reg], this wave's (wrow, kh) sub-tile

  for (int c = 0; c < Cn; ++c) {
    const int buf = c & 1;

    // issue next channel's prefetch BEFORE compute (hides under MFMA+sqrt)
    if (c + 1 < Cn) {
      stage_b(buf ^ 1, c + 1);   // async DMA into other Bs buffer
      load_x(c + 1);             // global loads into regs, waited at write_x
    }

    const char* bsb = (const char*)&Bs[buf][0];
    #pragma unroll
    for (int mt = 0; mt < 2; ++mt) {
      // xnorm + A fragments for this mt only (limits live regs: 4 + 8)
      float4 xn = *(const float4*)(&xnormC[c * WT + wbase + mt * 16 + quad * 4]);
      short8 a0, a1;
      {
        int i0 = wbase + mt * 16 + n16 + quad * 8;          // ks=0
        a0 = *(const short8*)(&Xr[buf][(i0 & 7) * XRS + (i0 >> 3) * 8]);
        int i1 = i0 + 32;                                    // ks=1
        a1 = *(const short8*)(&Xr[buf][(i1 & 7) * XRS + (i1 >> 3) * 8]);
      }
      #pragma unroll
      for (int nt = 0; nt < 4; ++nt) {
        int ksh = kh * 64 + nt * 16 + n16;                  // this wave's k-rows
        float sn = snormC[c * Kn + ksh];
        int boff = (ksh * 128 + quad * 16) ^ ((ksh & 7) << 4);
        short8 b0 = *(const short8*)(bsb + (boff ^ 0));
        short8 b1 = *(const short8*)(bsb + (boff ^ 64));    // ks=1: +64B, swizzle-safe
        f32x4 acc;
        #pragma unroll
        for (int rg = 0; rg < 4; ++rg) acc[rg] = xn[rg] + sn;
        acc = __builtin_amdgcn_mfma_f32_16x16x32_bf16(a0, b0, acc, 0, 0, 0);
        acc = __builtin_amdgcn_mfma_f32_16x16x32_bf16(a1, b1, acc, 0, 0, 0);
        // acc == d2 (norms preloaded in C, -2 folded into B)
        #pragma unroll
        for (int rg = 0; rg < 4; ++rg)
          dist[mt][nt][rg] += __builtin_amdgcn_sqrtf(acc[rg]);
      }
    }

    // late half of async-STAGE: convert + write next x tile into other buffer
    if (c + 1 < Cn) write_x(buf ^ 1);
    __syncthreads();  // one barrier per c-iter: publishes Xr writes + drains Bs DMA
  }

  // ---- min over windows, then global combine ----
  const int wql = w0 + wbase + quad * 4;
  #pragma unroll
  for (int nt = 0; nt < 4; ++nt) {
    float v = 3.4e38f;
    #pragma unroll
    for (int mt = 0; mt < 2; ++mt)
      #pragma unroll
      for (int rg = 0; rg < 4; ++rg) {
        int wg = wql + mt * 16 + rg;
        float d = (wg < Wn) ? dist[mt][nt][rg] : 3.4e38f;
        v = fminf(v, d);
      }
    v = fminf(v, __shfl_xor(v, 16, 64));
    v = fminf(v, __shfl_xor(v, 32, 64));
    if (lane < 16)
      atomicMin(&out[b * Kn + kh * 64 + nt * 16 + n16], __float_as_uint(v));
  }
}

extern "C" void kernel_launch(void* const* d_in, const int* in_sizes, int n_in,
                              void* d_out, int out_size, void* d_ws, size_t ws_size,
                              hipStream_t stream) {
  const float* x  = (const float*)d_in[0];
  const float* sh = (const float*)d_in[1];
  unsigned int* out = (unsigned int*)d_out;
  unsigned short* hbf = (unsigned short*)d_ws;                      // 128 KB
  float* snorm = (float*)((char*)d_ws + (size_t)Cn * Kn * Sn * 2);  // +4 KB
  hipLaunchKernelGGL(prep_kernel, dim3(16), dim3(256), 0, stream, sh, out, hbf, snorm);
  hipLaunchKernelGGL(med_kernel, dim3(NWT, Bn), dim3(BDIM), 0, stream, x, hbf, snorm, out);
}